// Round 3
// baseline (140.586 us; speedup 1.0000x reference)
//
#include <hip/hip_runtime.h>
#include <hip/hip_cooperative_groups.h>

// Problem constants (B=128 states, n=16 qubits, D=2^16 amplitudes).
#define BATCH 128
#define DIM 65536
#define HALF 32768
#define CHUNKS 8
#define CHUNK_PAIRS (HALF / CHUNKS)   // 4096 pairs per block
#define TPB 256                       // 16 pairs/thread = 4x float4 per stream

// Math: out[b] = cos^2(t)*sum(|a|^2-|b|^2) - 2 sin(t)*Re<a,b> + 2 sin(t)cos(t)*Im<a,b>
// where t = thetas[0], a = first half (bit0=0), b = second half (bit0=1).
// CNOT ladder commutes with Z_0; single-qubit gates on qubits 1..15 cancel.
//
// Single cooperative kernel: phase 1 writes one coefficient-applied partial
// per (batch, chunk) to ws via device-scope atomic stores (cross-XCD L2s are
// non-coherent); grid.sync(); phase 2 (block 0, 128 threads) sums CHUNKS
// partials per batch and writes out. No memset node, no tail kernel.

namespace cg = cooperative_groups;

__global__ __launch_bounds__(TPB) void qcirc_coop(
    const float* __restrict__ re, const float* __restrict__ im,
    const float* __restrict__ thetas, float* __restrict__ out,
    float* __restrict__ ws)
{
    const int b = blockIdx.y;
    const int chunk = blockIdx.x;
    const int t = threadIdx.x;

    const float* ra_p = re + (size_t)b * DIM;        // re, bit0 = 0 half
    const float* rb_p = ra_p + HALF;                 // re, bit0 = 1 half
    const float* ia_p = im + (size_t)b * DIM;        // im, bit0 = 0 half
    const float* ib_p = ia_p + HALF;                 // im, bit0 = 1 half

    const int base = chunk * CHUNK_PAIRS;

    float diff = 0.f;   // sum |a|^2 - |b|^2
    float dre  = 0.f;   // Re sum conj(a)*b
    float dim_ = 0.f;   // Im sum conj(a)*b

    #pragma unroll
    for (int i = 0; i < CHUNK_PAIRS / (TPB * 4); ++i) {
        const int r = base + (i * TPB + t) * 4;      // coalesced float4
        const float4 ra = *reinterpret_cast<const float4*>(ra_p + r);
        const float4 ia = *reinterpret_cast<const float4*>(ia_p + r);
        const float4 rb = *reinterpret_cast<const float4*>(rb_p + r);
        const float4 ib = *reinterpret_cast<const float4*>(ib_p + r);

        diff += ra.x*ra.x + ia.x*ia.x - rb.x*rb.x - ib.x*ib.x;
        diff += ra.y*ra.y + ia.y*ia.y - rb.y*rb.y - ib.y*ib.y;
        diff += ra.z*ra.z + ia.z*ia.z - rb.z*rb.z - ib.z*ib.z;
        diff += ra.w*ra.w + ia.w*ia.w - rb.w*rb.w - ib.w*ib.w;

        dre  += ra.x*rb.x + ia.x*ib.x;
        dre  += ra.y*rb.y + ia.y*ib.y;
        dre  += ra.z*rb.z + ia.z*ib.z;
        dre  += ra.w*rb.w + ia.w*ib.w;

        dim_ += ra.x*ib.x - ia.x*rb.x;
        dim_ += ra.y*ib.y - ia.y*rb.y;
        dim_ += ra.z*ib.z - ia.z*rb.z;
        dim_ += ra.w*ib.w - ia.w*rb.w;
    }

    // wave64 butterfly reduce
    #pragma unroll
    for (int off = 32; off > 0; off >>= 1) {
        diff += __shfl_down(diff, off);
        dre  += __shfl_down(dre,  off);
        dim_ += __shfl_down(dim_, off);
    }

    __shared__ float sdata[3][TPB / 64];
    const int wave = t >> 6, lane = t & 63;
    if (lane == 0) {
        sdata[0][wave] = diff;
        sdata[1][wave] = dre;
        sdata[2][wave] = dim_;
    }
    __syncthreads();
    if (t == 0) {
        float d = 0.f, r = 0.f, ii = 0.f;
        #pragma unroll
        for (int w = 0; w < TPB / 64; ++w) {
            d += sdata[0][w]; r += sdata[1][w]; ii += sdata[2][w];
        }
        const float theta = thetas[0];
        const float ct = __cosf(theta);
        const float st = __sinf(theta);
        const float val = ct * ct * d - 2.f * st * r + 2.f * st * ct * ii;
        // device-scope store: must be visible across XCDs after grid.sync()
        __hip_atomic_store(&ws[(size_t)b * CHUNKS + chunk], val,
                           __ATOMIC_RELAXED, __HIP_MEMORY_SCOPE_AGENT);
    }

    cg::this_grid().sync();

    // phase 2: one block finalizes all 128 outputs
    if (blockIdx.x == 0 && blockIdx.y == 0 && t < BATCH) {
        float s = 0.f;
        #pragma unroll
        for (int c = 0; c < CHUNKS; ++c)
            s += __hip_atomic_load(&ws[(size_t)t * CHUNKS + c],
                                   __ATOMIC_RELAXED, __HIP_MEMORY_SCOPE_AGENT);
        out[t] = s;
    }
}

extern "C" void kernel_launch(void* const* d_in, const int* in_sizes, int n_in,
                              void* d_out, int out_size, void* d_ws, size_t ws_size,
                              hipStream_t stream) {
    const float* re     = (const float*)d_in[0];
    const float* im     = (const float*)d_in[1];
    const float* thetas = (const float*)d_in[2];
    float* out = (float*)d_out;
    float* ws  = (float*)d_ws;   // needs 128*8*4 = 4 KiB

    void* args[] = {(void*)&re, (void*)&im, (void*)&thetas, (void*)&out, (void*)&ws};
    hipLaunchCooperativeKernel((const void*)qcirc_coop,
                               dim3(CHUNKS, BATCH), dim3(TPB),
                               args, 0, stream);
}

// Round 4
// 17.112 us; speedup vs baseline: 8.2158x; 8.2158x over previous
//
#include <hip/hip_runtime.h>

// Problem constants (B=128 states, n=16 qubits, D=2^16 amplitudes).
#define BATCH 128
#define DIM 65536
#define HALF 32768
#define TPB 1024                     // 16 waves; one block per batch element
#define PER_THREAD_F4 8              // 32768 pairs / 1024 threads = 32 = 8 float4

// Math: out[b] = cos^2(t)*sum(|a|^2-|b|^2) - 2 sin(t)*Re<a,b> + 2 sin(t)cos(t)*Im<a,b>
// where t = thetas[0], a = first half (bit0=0), b = second half (bit0=1).
// CNOT ladder commutes with Z_0; single-qubit gates on qubits 1..15 cancel.
//
// One block per batch element: block-local reduction only, single dispatch,
// no memset / tail kernel / grid sync.

__global__ __launch_bounds__(TPB) void qcirc_block(
    const float* __restrict__ re, const float* __restrict__ im,
    const float* __restrict__ thetas, float* __restrict__ out)
{
    const int b = blockIdx.x;
    const int t = threadIdx.x;

    const float* ra_p = re + (size_t)b * DIM;        // re, bit0 = 0 half
    const float* rb_p = ra_p + HALF;                 // re, bit0 = 1 half
    const float* ia_p = im + (size_t)b * DIM;        // im, bit0 = 0 half
    const float* ib_p = ia_p + HALF;                 // im, bit0 = 1 half

    float diff = 0.f;   // sum |a|^2 - |b|^2
    float dre  = 0.f;   // Re sum conj(a)*b
    float dim_ = 0.f;   // Im sum conj(a)*b

    #pragma unroll
    for (int i = 0; i < PER_THREAD_F4; ++i) {
        const int r = (i * TPB + t) * 4;             // coalesced float4
        const float4 ra = *reinterpret_cast<const float4*>(ra_p + r);
        const float4 ia = *reinterpret_cast<const float4*>(ia_p + r);
        const float4 rb = *reinterpret_cast<const float4*>(rb_p + r);
        const float4 ib = *reinterpret_cast<const float4*>(ib_p + r);

        diff += ra.x*ra.x + ia.x*ia.x - rb.x*rb.x - ib.x*ib.x;
        diff += ra.y*ra.y + ia.y*ia.y - rb.y*rb.y - ib.y*ib.y;
        diff += ra.z*ra.z + ia.z*ia.z - rb.z*rb.z - ib.z*ib.z;
        diff += ra.w*ra.w + ia.w*ia.w - rb.w*rb.w - ib.w*ib.w;

        dre  += ra.x*rb.x + ia.x*ib.x;
        dre  += ra.y*rb.y + ia.y*ib.y;
        dre  += ra.z*rb.z + ia.z*ib.z;
        dre  += ra.w*rb.w + ia.w*ib.w;

        dim_ += ra.x*ib.x - ia.x*rb.x;
        dim_ += ra.y*ib.y - ia.y*rb.y;
        dim_ += ra.z*ib.z - ia.z*rb.z;
        dim_ += ra.w*ib.w - ia.w*rb.w;
    }

    // wave64 butterfly reduce
    #pragma unroll
    for (int off = 32; off > 0; off >>= 1) {
        diff += __shfl_down(diff, off);
        dre  += __shfl_down(dre,  off);
        dim_ += __shfl_down(dim_, off);
    }

    __shared__ float sdata[3][TPB / 64];             // 16 waves
    const int wave = t >> 6, lane = t & 63;
    if (lane == 0) {
        sdata[0][wave] = diff;
        sdata[1][wave] = dre;
        sdata[2][wave] = dim_;
    }
    __syncthreads();

    if (t < 16) {
        float d = sdata[0][t], r = sdata[1][t], ii = sdata[2][t];
        #pragma unroll
        for (int off = 8; off > 0; off >>= 1) {
            d  += __shfl_down(d,  off);
            r  += __shfl_down(r,  off);
            ii += __shfl_down(ii, off);
        }
        if (t == 0) {
            const float theta = thetas[0];
            const float ct = __cosf(theta);
            const float st = __sinf(theta);
            out[b] = ct * ct * d - 2.f * st * r + 2.f * st * ct * ii;
        }
    }
}

extern "C" void kernel_launch(void* const* d_in, const int* in_sizes, int n_in,
                              void* d_out, int out_size, void* d_ws, size_t ws_size,
                              hipStream_t stream) {
    const float* re     = (const float*)d_in[0];
    const float* im     = (const float*)d_in[1];
    const float* thetas = (const float*)d_in[2];
    float* out = (float*)d_out;

    qcirc_block<<<BATCH, TPB, 0, stream>>>(re, im, thetas, out);
}

// Round 5
// 15.677 us; speedup vs baseline: 8.9677x; 1.0915x over previous
//
#include <hip/hip_runtime.h>

// Problem constants (B=128 states, n=16 qubits, D=2^16 amplitudes).
#define BATCH 128
#define DIM 65536
#define HALF 32768
#define TPB 1024                     // 16 waves; one block per batch element
#define ITERS 8                      // 32768 pairs / 1024 threads = 32 = 8 float4

// Math: out[b] = cos^2(t)*sum(|a|^2-|b|^2) - 2 sin(t)*Re<a,b> + 2 sin(t)cos(t)*Im<a,b>
// where t = thetas[0], a = first half (bit0=0), b = second half (bit0=1).
// CNOT ladder commutes with Z_0; single-qubit gates on qubits 1..15 cancel.
//
// One block per batch element (single dispatch — R2/R3 showed every extra
// graph node costs ~5-7 us). This round: explicit 2-deep register pipeline
// (prefetch next 4x float4 while accumulating current) to raise per-wave MLP;
// R3's VGPR_Count=32 showed the compiler was serializing loads.

#define LD4(p) (*reinterpret_cast<const float4*>(p))

__global__ __launch_bounds__(TPB, 4) void qcirc_block(
    const float* __restrict__ re, const float* __restrict__ im,
    const float* __restrict__ thetas, float* __restrict__ out)
{
    const int b = blockIdx.x;
    const int t = threadIdx.x;

    const float* ra_p = re + (size_t)b * DIM;        // re, bit0 = 0 half
    const float* rb_p = ra_p + HALF;                 // re, bit0 = 1 half
    const float* ia_p = im + (size_t)b * DIM;        // im, bit0 = 0 half
    const float* ib_p = ia_p + HALF;                 // im, bit0 = 1 half

    // two accumulator sets to break the serial FMA chain
    float diff0 = 0.f, diff1 = 0.f;
    float dre0  = 0.f, dre1  = 0.f;
    float dim0  = 0.f, dim1  = 0.f;

    // prologue: load iteration 0
    int r = t * 4;
    float4 cra = LD4(ra_p + r), cia = LD4(ia_p + r);
    float4 crb = LD4(rb_p + r), cib = LD4(ib_p + r);

    #pragma unroll
    for (int i = 0; i < ITERS; ++i) {
        float4 nra, nia, nrb, nib;
        if (i < ITERS - 1) {
            const int rn = ((i + 1) * TPB + t) * 4;  // coalesced float4
            nra = LD4(ra_p + rn); nia = LD4(ia_p + rn);
            nrb = LD4(rb_p + rn); nib = LD4(ib_p + rn);
        }

        if ((i & 1) == 0) {
            diff0 += cra.x*cra.x + cia.x*cia.x - crb.x*crb.x - cib.x*cib.x;
            diff0 += cra.y*cra.y + cia.y*cia.y - crb.y*crb.y - cib.y*cib.y;
            diff0 += cra.z*cra.z + cia.z*cia.z - crb.z*crb.z - cib.z*cib.z;
            diff0 += cra.w*cra.w + cia.w*cia.w - crb.w*crb.w - cib.w*cib.w;
            dre0  += cra.x*crb.x + cia.x*cib.x + cra.y*crb.y + cia.y*cib.y;
            dre0  += cra.z*crb.z + cia.z*cib.z + cra.w*crb.w + cia.w*cib.w;
            dim0  += cra.x*cib.x - cia.x*crb.x + cra.y*cib.y - cia.y*crb.y;
            dim0  += cra.z*cib.z - cia.z*crb.z + cra.w*cib.w - cia.w*crb.w;
        } else {
            diff1 += cra.x*cra.x + cia.x*cia.x - crb.x*crb.x - cib.x*cib.x;
            diff1 += cra.y*cra.y + cia.y*cia.y - crb.y*crb.y - cib.y*cib.y;
            diff1 += cra.z*cra.z + cia.z*cia.z - crb.z*crb.z - cib.z*cib.z;
            diff1 += cra.w*cra.w + cia.w*cia.w - crb.w*crb.w - cib.w*cib.w;
            dre1  += cra.x*crb.x + cia.x*cib.x + cra.y*crb.y + cia.y*cib.y;
            dre1  += cra.z*crb.z + cia.z*cib.z + cra.w*crb.w + cia.w*cib.w;
            dim1  += cra.x*cib.x - cia.x*crb.x + cra.y*cib.y - cia.y*crb.y;
            dim1  += cra.z*cib.z - cia.z*crb.z + cra.w*cib.w - cia.w*crb.w;
        }

        if (i < ITERS - 1) { cra = nra; cia = nia; crb = nrb; cib = nib; }
    }

    float diff = diff0 + diff1;
    float dre  = dre0 + dre1;
    float dim_ = dim0 + dim1;

    // wave64 butterfly reduce
    #pragma unroll
    for (int off = 32; off > 0; off >>= 1) {
        diff += __shfl_down(diff, off);
        dre  += __shfl_down(dre,  off);
        dim_ += __shfl_down(dim_, off);
    }

    __shared__ float sdata[3][TPB / 64];             // 16 waves
    const int wave = t >> 6, lane = t & 63;
    if (lane == 0) {
        sdata[0][wave] = diff;
        sdata[1][wave] = dre;
        sdata[2][wave] = dim_;
    }
    __syncthreads();

    if (t < 16) {
        float d = sdata[0][t], rr = sdata[1][t], ii = sdata[2][t];
        #pragma unroll
        for (int off = 8; off > 0; off >>= 1) {
            d  += __shfl_down(d,  off);
            rr += __shfl_down(rr, off);
            ii += __shfl_down(ii, off);
        }
        if (t == 0) {
            const float theta = thetas[0];
            const float ct = __cosf(theta);
            const float st = __sinf(theta);
            out[b] = ct * ct * d - 2.f * st * rr + 2.f * st * ct * ii;
        }
    }
}

extern "C" void kernel_launch(void* const* d_in, const int* in_sizes, int n_in,
                              void* d_out, int out_size, void* d_ws, size_t ws_size,
                              hipStream_t stream) {
    const float* re     = (const float*)d_in[0];
    const float* im     = (const float*)d_in[1];
    const float* thetas = (const float*)d_in[2];
    float* out = (float*)d_out;

    qcirc_block<<<BATCH, TPB, 0, stream>>>(re, im, thetas, out);
}